// Round 3
// baseline (405.388 us; speedup 1.0000x reference)
//
#include <hip/hip_runtime.h>
#include <hip/hip_bf16.h>

#define NB 8
#define C 256
#define LL 6400
#define HEADS 8
#define HC 32
#define NH 64      // NB*HEADS
#define KCHUNKS 25 // kstats l-chunks of 256

typedef unsigned short u16;
typedef unsigned int u32;
typedef __attribute__((ext_vector_type(8))) short bf16x8;
typedef __attribute__((ext_vector_type(4))) float f32x4;

typedef __attribute__((address_space(1))) const u32 ga_u32;
typedef __attribute__((address_space(3))) u32 ls_u32;

__device__ __forceinline__ void gload_lds16(const u16* g, u16* l) {
  __builtin_amdgcn_global_load_lds((ga_u32*)g, (ls_u32*)l, 16, 0, 0);
}

__device__ __forceinline__ float bf2f(u32 u) { return __uint_as_float(u << 16); }
__device__ __forceinline__ u16 f2bf(float f) {
  __hip_bfloat16 h = __float2bfloat16(f);
  return *(u16*)&h;
}
__device__ __forceinline__ void unpack8(uint4 u, float* f) {
  f[0] = bf2f(u.x & 0xffffu); f[1] = bf2f(u.x >> 16);
  f[2] = bf2f(u.y & 0xffffu); f[3] = bf2f(u.y >> 16);
  f[4] = bf2f(u.z & 0xffffu); f[5] = bf2f(u.z >> 16);
  f[6] = bf2f(u.w & 0xffffu); f[7] = bf2f(u.w >> 16);
}

struct TransArgs { const float* X[3]; u16* Xt[3]; };
struct ProjArgs { const u16* Xt[3]; const float* W[3]; const float* bias[3]; u16* P[3]; };

// ---------------- fp32 [C][L] -> bf16 [L][C] transpose+convert, 3 inputs ----------------
__global__ __launch_bounds__(256) void trans3(TransArgs args) {
  __shared__ float tl[64][65];
  const int which = blockIdx.z >> 3, n = blockIdx.z & 7;
  const int l0 = blockIdx.x * 64, c0 = blockIdx.y * 64;
  const int t = threadIdx.x;
  const int rr = t >> 4;
  const int lc = (t & 15) * 4;
  const float* Xn = args.X[which] + (size_t)n * C * LL;
#pragma unroll
  for (int p = 0; p < 4; ++p) {
    const int row = p * 16 + rr;  // c within tile
    float4 v = *(const float4*)&Xn[(size_t)(c0 + row) * LL + l0 + lc];
    tl[row][lc + 0] = v.x; tl[row][lc + 1] = v.y;
    tl[row][lc + 2] = v.z; tl[row][lc + 3] = v.w;
  }
  __syncthreads();
  u16* XtN = args.Xt[which] + (size_t)n * LL * C;
  const int cc = (t & 15) * 4;
#pragma unroll
  for (int p = 0; p < 4; ++p) {
    const int lrow = p * 16 + rr;  // l within tile
    ushort4 o;
    o.x = f2bf(tl[cc + 0][lrow]); o.y = f2bf(tl[cc + 1][lrow]);
    o.z = f2bf(tl[cc + 2][lrow]); o.w = f2bf(tl[cc + 3][lrow]);
    *(ushort4*)&XtN[(size_t)(l0 + lrow) * C + c0 + cc] = o;
  }
}

// ---------------- proj (x3): Pt[l][co] = sum_k Xt[l][k]*W[co][k] + b, bf16 out ----------
// 128x128 tile, BK=32, 4 waves 2x2. W converted fp32->bf16 inline during staging.
__global__ __launch_bounds__(256) void proj3(ProjArgs args) {
  __shared__ __align__(16) u16 As[4096];  // [128 l][32 k]
  __shared__ __align__(16) u16 Bs[4096];  // [128 co][32 k]
  const int which = blockIdx.z >> 3, n = blockIdx.z & 7;
  const int co0 = blockIdx.x * 128;
  const int l0 = blockIdx.y * 128;
  const int t = threadIdx.x;
  const int lane = t & 63, wave = t >> 6;
  const int wm = (wave >> 1) * 64, wn = (wave & 1) * 64;
  const int srow = t >> 2;         // 0..63
  const int scol = (t & 3) * 8;
  const int brow = t >> 1;         // 0..127 (W staging row)
  const int bkh = (t & 1) * 16;    // W staging k-half
  const u16* XtN = args.Xt[which] + (size_t)n * LL * C;
  const float* W = args.W[which];
  f32x4 acc[4][4] = {};
  for (int k0 = 0; k0 < C; k0 += 32) {
    __syncthreads();
    gload_lds16(&XtN[(size_t)(l0 + srow) * C + k0 + scol], &As[wave * 512]);
    gload_lds16(&XtN[(size_t)(l0 + 64 + srow) * C + k0 + scol], &As[2048 + wave * 512]);
    {
      const float* wp = &W[(size_t)(co0 + brow) * C + k0 + bkh];
      float4 w0 = *(const float4*)&wp[0];
      float4 w1 = *(const float4*)&wp[4];
      float4 w2 = *(const float4*)&wp[8];
      float4 w3 = *(const float4*)&wp[12];
      union { uint4 u; u16 h[8]; } p0, p1;
      p0.h[0] = f2bf(w0.x); p0.h[1] = f2bf(w0.y); p0.h[2] = f2bf(w0.z); p0.h[3] = f2bf(w0.w);
      p0.h[4] = f2bf(w1.x); p0.h[5] = f2bf(w1.y); p0.h[6] = f2bf(w1.z); p0.h[7] = f2bf(w1.w);
      p1.h[0] = f2bf(w2.x); p1.h[1] = f2bf(w2.y); p1.h[2] = f2bf(w2.z); p1.h[3] = f2bf(w2.w);
      p1.h[4] = f2bf(w3.x); p1.h[5] = f2bf(w3.y); p1.h[6] = f2bf(w3.z); p1.h[7] = f2bf(w3.w);
      *(uint4*)&Bs[brow * 32 + bkh] = p0.u;
      *(uint4*)&Bs[brow * 32 + bkh + 8] = p1.u;
    }
    __syncthreads();
    const int fr = lane & 15, quad = lane >> 4;
    bf16x8 a[4], b[4];
#pragma unroll
    for (int i = 0; i < 4; ++i)
      a[i] = *(const bf16x8*)&As[(wm + i * 16 + fr) * 32 + quad * 8];
#pragma unroll
    for (int j = 0; j < 4; ++j)
      b[j] = *(const bf16x8*)&Bs[(wn + j * 16 + fr) * 32 + quad * 8];
#pragma unroll
    for (int i = 0; i < 4; ++i)
#pragma unroll
      for (int j = 0; j < 4; ++j)
        acc[i][j] = __builtin_amdgcn_mfma_f32_16x16x32_bf16(a[i], b[j], acc[i][j], 0, 0, 0);
  }
  u16* PtN = args.P[which] + (size_t)n * LL * C;
  const float* bias = args.bias[which];
  const int fr = lane & 15, quad = lane >> 4;
  const int colc = co0 + wn + fr;
  float bv[4];
#pragma unroll
  for (int j = 0; j < 4; ++j) bv[j] = bias[colc + j * 16];
#pragma unroll
  for (int i = 0; i < 4; ++i) {
    const int lrow = l0 + wm + i * 16 + quad * 4;
#pragma unroll
    for (int r = 0; r < 4; ++r)
#pragma unroll
      for (int j = 0; j < 4; ++j)
        PtN[(size_t)(lrow + r) * C + colc + j * 16] = f2bf(acc[i][j][r] + bv[j]);
  }
}

// ---------------- k stats over [L][C]: per-chunk max + sumexp partials ----------------
__global__ __launch_bounds__(256) void kstats(const u16* __restrict__ Kt,
    float* __restrict__ pmax, float* __restrict__ psum) {
  const int chk = blockIdx.x, n = blockIdx.y;
  const int t = threadIdx.x;
  const int c2 = t & 127, ph = t >> 7;
  const u16* base = Kt + ((size_t)n * LL + chk * 256) * C + c2 * 2;
  float m0 = -1e30f, m1 = -1e30f;
  for (int i = 0; i < 128; ++i) {
    u32 u = *(const u32*)&base[(size_t)(2 * i + ph) * C];
    m0 = fmaxf(m0, bf2f(u & 0xffffu)); m1 = fmaxf(m1, bf2f(u >> 16));
  }
  __shared__ float sm[2][256];
  sm[ph][c2 * 2] = m0; sm[ph][c2 * 2 + 1] = m1;
  __syncthreads();
  m0 = fmaxf(sm[0][c2 * 2], sm[1][c2 * 2]);
  m1 = fmaxf(sm[0][c2 * 2 + 1], sm[1][c2 * 2 + 1]);
  float s0 = 0.f, s1 = 0.f;
  for (int i = 0; i < 128; ++i) {
    u32 u = *(const u32*)&base[(size_t)(2 * i + ph) * C];
    s0 += __expf(bf2f(u & 0xffffu) - m0);
    s1 += __expf(bf2f(u >> 16) - m1);
  }
  __syncthreads();
  sm[ph][c2 * 2] = s0; sm[ph][c2 * 2 + 1] = s1;
  __syncthreads();
  if (ph == 0) {
    const int idx = (n * KCHUNKS + chk) * 256 + c2 * 2;
    pmax[idx] = m0; pmax[idx + 1] = m1;
    psum[idx] = sm[0][c2 * 2] + sm[1][c2 * 2];
    psum[idx + 1] = sm[0][c2 * 2 + 1] + sm[1][c2 * 2 + 1];
  }
}

// ---------------- ctx partials: merge stats + K-softmax @ V^T, 4 l-segments ----------
// grid (4, NH), 256 thr. part[seg][nh][k][v] (krs pre-applied). mfuse sums the 4.
__global__ __launch_bounds__(256) void ctx_fused(const u16* __restrict__ Kt,
    const u16* __restrict__ Vt, const float* __restrict__ pmax,
    const float* __restrict__ psum, float* __restrict__ part) {
  __shared__ float kms[HC], krss[HC];
  __shared__ float Ks[4][16][36];
  __shared__ float Vs[4][16][36];
  __shared__ float red[4][HC][HC];
  const int nh = blockIdx.y, seg = blockIdx.x;
  const int n = nh >> 3, h = nh & 7;
  const int t = threadIdx.x, w = t >> 6, lane = t & 63;
  if (t < HC) {
    const int c = h * HC + t;
    float m = -1e30f;
    for (int ch = 0; ch < KCHUNKS; ++ch)
      m = fmaxf(m, pmax[(n * KCHUNKS + ch) * C + c]);
    float s = 0.f;
    for (int ch = 0; ch < KCHUNKS; ++ch)
      s += psum[(n * KCHUNKS + ch) * C + c] * __expf(pmax[(n * KCHUNKS + ch) * C + c] - m);
    kms[t] = m; krss[t] = 1.0f / s;
  }
  __syncthreads();
  const int r16 = lane >> 2, coff = (lane & 3) * 8;
  float km[8];
#pragma unroll
  for (int j = 0; j < 8; ++j) km[j] = kms[coff + j];
  const int k4 = (lane & 7) * 4, v4 = (lane >> 3) * 4;
  float acc[4][4];
#pragma unroll
  for (int i = 0; i < 4; ++i)
#pragma unroll
    for (int j = 0; j < 4; ++j) acc[i][j] = 0.f;
  for (int it = 0; it < 25; ++it) {
    const int lbase = seg * 1600 + (it * 4 + w) * 16;
    const size_t off = ((size_t)n * LL + lbase + r16) * C + h * HC + coff;
    uint4 ku = *(const uint4*)&Kt[off];
    uint4 vu = *(const uint4*)&Vt[off];
    float kf[8], vf[8];
    unpack8(ku, kf); unpack8(vu, vf);
    __syncthreads();
#pragma unroll
    for (int j = 0; j < 8; ++j) {
      Ks[w][r16][coff + j] = __expf(kf[j] - km[j]);
      Vs[w][r16][coff + j] = vf[j];
    }
    __syncthreads();
#pragma unroll
    for (int l = 0; l < 16; ++l) {
      float a[4], b[4];
      *(float4*)a = *(const float4*)&Ks[w][l][k4];
      *(float4*)b = *(const float4*)&Vs[w][l][v4];
#pragma unroll
      for (int i = 0; i < 4; ++i)
#pragma unroll
        for (int j = 0; j < 4; ++j) acc[i][j] = fmaf(a[i], b[j], acc[i][j]);
    }
  }
#pragma unroll
  for (int i = 0; i < 4; ++i) {
    const float rs = krss[k4 + i];
#pragma unroll
    for (int j = 0; j < 4; ++j) red[w][k4 + i][v4 + j] = acc[i][j] * rs;
  }
  __syncthreads();
  const float* rf = &red[0][0][0];
  const int e0 = t * 4;
  float4 o;
  o.x = rf[e0 + 0] + rf[1024 + e0 + 0] + rf[2048 + e0 + 0] + rf[3072 + e0 + 0];
  o.y = rf[e0 + 1] + rf[1024 + e0 + 1] + rf[2048 + e0 + 1] + rf[3072 + e0 + 1];
  o.z = rf[e0 + 2] + rf[1024 + e0 + 2] + rf[2048 + e0 + 2] + rf[3072 + e0 + 2];
  o.w = rf[e0 + 3] + rf[1024 + e0 + 3] + rf[2048 + e0 + 3] + rf[3072 + e0 + 3];
  *(float4*)&part[((size_t)seg * NH + nh) * (HC * HC) + e0] = o;
}

// ---------------- fuse: M_n[o, h*32+k] = sum_v Wr[o,h*32+v]*ctx[n,h,k,v], bf16 out ------
__global__ __launch_bounds__(256) void mfuse(const float* __restrict__ Wr,
    const float* __restrict__ part, u16* __restrict__ M) {
  const int idx = blockIdx.x * 256 + threadIdx.x;  // < NB*C*C
  const int hk = idx & 255;
  const int o = (idx >> 8) & 255;
  const int n = idx >> 16;
  const int h = hk >> 5, k = hk & 31;
  const float* wr = Wr + (size_t)o * C + h * HC;
  const float* p0 = part + ((size_t)(n * HEADS + h)) * (HC * HC) + k * HC;
  const size_t segstr = (size_t)NH * HC * HC;
  float s = 0.f;
#pragma unroll
  for (int v = 0; v < HC; ++v) {
    float cv = p0[v] + p0[segstr + v] + p0[2 * segstr + v] + p0[3 * segstr + v];
    s = fmaf(wr[v], cv, s);
  }
  M[idx] = f2bf(s);
}

// ---- out[co][l] = sum_k M[co][k]*softmaxQ[l][k] + br[co] + Xq[co][l], fp32 ----
// q-softmax fused into B-staging: each K-block of 32 channels == one head.
__global__ __launch_bounds__(256) void out3(const u16* __restrict__ Qt,
    const u16* __restrict__ Mb, const float* __restrict__ br,
    const float* __restrict__ Xq, float* __restrict__ out) {
  __shared__ __align__(16) u16 As[4096];  // [128 co][32 k]
  __shared__ __align__(16) u16 Bs[4096];  // [128 l][32 k]
  const int n = blockIdx.z;
  const int co0 = blockIdx.x * 128;
  const int l0 = blockIdx.y * 128;
  const int t = threadIdx.x;
  const int lane = t & 63, wave = t >> 6;
  const int wm = (wave >> 1) * 64, wn = (wave & 1) * 64;
  const int srow = t >> 2;       // A staging row (0..63)
  const int scol = (t & 3) * 8;  // A staging k offset
  const int brow = t >> 2;       // B row 0..63 (two passes)
  const int bsc = (t & 3) * 8;
  const u16* MbN = Mb + (size_t)n * C * C;
  const u16* QtN = Qt + (size_t)n * LL * C;
  f32x4 acc[4][4] = {};
  for (int k0 = 0; k0 < C; k0 += 32) {
    __syncthreads();
    gload_lds16(&MbN[(size_t)(co0 + srow) * C + k0 + scol], &As[wave * 512]);
    gload_lds16(&MbN[(size_t)(co0 + 64 + srow) * C + k0 + scol], &As[2048 + wave * 512]);
#pragma unroll
    for (int p = 0; p < 2; ++p) {
      const int row = p * 64 + brow;
      uint4 u = *(const uint4*)&QtN[(size_t)(l0 + row) * C + k0 + bsc];
      float v[8]; unpack8(u, v);
      float m = v[0];
#pragma unroll
      for (int j = 1; j < 8; ++j) m = fmaxf(m, v[j]);
      m = fmaxf(m, __shfl_xor(m, 1));
      m = fmaxf(m, __shfl_xor(m, 2));
      float e[8], s = 0.f;
#pragma unroll
      for (int j = 0; j < 8; ++j) { e[j] = __expf(v[j] - m); s += e[j]; }
      s += __shfl_xor(s, 1);
      s += __shfl_xor(s, 2);
      const float r = 1.0f / s;
      union { uint4 u; u16 h[8]; } o;
#pragma unroll
      for (int j = 0; j < 8; ++j) o.h[j] = f2bf(e[j] * r);
      *(uint4*)&Bs[row * 32 + bsc] = o.u;
    }
    __syncthreads();
    const int fr = lane & 15, quad = lane >> 4;
    bf16x8 a[4], b[4];
#pragma unroll
    for (int i = 0; i < 4; ++i)
      a[i] = *(const bf16x8*)&As[(wm + i * 16 + fr) * 32 + quad * 8];
#pragma unroll
    for (int j = 0; j < 4; ++j)
      b[j] = *(const bf16x8*)&Bs[(wn + j * 16 + fr) * 32 + quad * 8];
#pragma unroll
    for (int i = 0; i < 4; ++i)
#pragma unroll
      for (int j = 0; j < 4; ++j)
        acc[i][j] = __builtin_amdgcn_mfma_f32_16x16x32_bf16(a[i], b[j], acc[i][j], 0, 0, 0);
  }
  const float* XqN = Xq + (size_t)n * C * LL;
  float* On = out + (size_t)n * C * LL;
  const int fr = lane & 15, quad = lane >> 4;
#pragma unroll
  for (int i = 0; i < 4; ++i) {
#pragma unroll
    for (int r = 0; r < 4; ++r) {
      const int co = co0 + wm + i * 16 + quad * 4 + r;
      const float bb = br[co];
#pragma unroll
      for (int j = 0; j < 4; ++j) {
        const int l = l0 + wn + j * 16 + fr;
        const size_t off = (size_t)co * LL + l;
        On[off] = acc[i][j][r] + bb + XqN[off];
      }
    }
  }
}

extern "C" void kernel_launch(void* const* d_in, const int* in_sizes, int n_in,
                              void* d_out, int out_size, void* d_ws, size_t ws_size,
                              hipStream_t stream) {
  const float* Xq = (const float*)d_in[0];
  const float* Xk = (const float*)d_in[1];
  const float* Xv = (const float*)d_in[2];
  const float* Wq = (const float*)d_in[3];
  const float* bq = (const float*)d_in[4];
  const float* Wk = (const float*)d_in[5];
  const float* bk = (const float*)d_in[6];
  const float* Wv = (const float*)d_in[7];
  const float* bv = (const float*)d_in[8];
  const float* Wr = (const float*)d_in[9];
  const float* br = (const float*)d_in[10];
  float* out = (float*)d_out;

  char* ws = (char*)d_ws;
  const size_t nelem = (size_t)NB * LL * C;  // per [L][C] buffer (u16)
  u16* Xtq = (u16*)ws;
  u16* Xtk = (u16*)(ws + nelem * 2);
  u16* Xtv = (u16*)(ws + nelem * 4);
  u16* Qt = (u16*)(ws + nelem * 6);
  u16* Kt = (u16*)(ws + nelem * 8);
  u16* Vt = (u16*)(ws + nelem * 10);
  char* p = ws + nelem * 12;
  float* pmax = (float*)p; p += KCHUNKS * NB * C * 4;
  float* psum = (float*)p; p += KCHUNKS * NB * C * 4;
  float* part = (float*)p; p += (size_t)4 * NH * HC * HC * 4;
  u16* Mb = (u16*)p;

  TransArgs ta;
  ta.X[0] = Xq; ta.X[1] = Xk; ta.X[2] = Xv;
  ta.Xt[0] = Xtq; ta.Xt[1] = Xtk; ta.Xt[2] = Xtv;
  trans3<<<dim3(100, 4, 24), 256, 0, stream>>>(ta);

  ProjArgs pa;
  pa.Xt[0] = Xtq; pa.Xt[1] = Xtk; pa.Xt[2] = Xtv;
  pa.W[0] = Wq; pa.W[1] = Wk; pa.W[2] = Wv;
  pa.bias[0] = bq; pa.bias[1] = bk; pa.bias[2] = bv;
  pa.P[0] = Qt; pa.P[1] = Kt; pa.P[2] = Vt;
  proj3<<<dim3(2, 50, 24), 256, 0, stream>>>(pa);

  kstats<<<dim3(KCHUNKS, NB), 256, 0, stream>>>(Kt, pmax, psum);
  ctx_fused<<<dim3(4, NH), 256, 0, stream>>>(Kt, Vt, pmax, psum, part);
  mfuse<<<NB * C * C / 256, 256, 0, stream>>>(Wr, part, Mb);
  out3<<<dim3(2, 50, NB), 256, 0, stream>>>(Qt, Mb, br, Xq, out);
}

// Round 4
// 347.722 us; speedup vs baseline: 1.1658x; 1.1658x over previous
//
#include <hip/hip_runtime.h>
#include <hip/hip_bf16.h>

#define NB 8
#define C 256
#define LL 6400
#define HEADS 8
#define HC 32
#define NH 64      // NB*HEADS
#define SEG 40     // ctx l-segments
#define SL 160     // LL / SEG
#define ATP 40     // proj At pitch (u16), 80B rows -> 16B-aligned b128 frags
#define QPP 264    // out Q-panel pitch (u16)

typedef unsigned short u16;
typedef unsigned int u32;
typedef __attribute__((ext_vector_type(8))) short bf16x8;
typedef __attribute__((ext_vector_type(4))) float f32x4;

typedef __attribute__((address_space(1))) const u32 ga_u32;
typedef __attribute__((address_space(3))) u32 ls_u32;

__device__ __forceinline__ void gload_lds16(const u16* g, u16* l) {
  __builtin_amdgcn_global_load_lds((ga_u32*)g, (ls_u32*)l, 16, 0, 0);
}

__device__ __forceinline__ float bf2f(u32 u) { return __uint_as_float(u << 16); }
__device__ __forceinline__ u16 f2bf(float f) {
  __hip_bfloat16 h = __float2bfloat16(f);
  return *(u16*)&h;
}
__device__ __forceinline__ void unpack8(uint4 u, float* f) {
  f[0] = bf2f(u.x & 0xffffu); f[1] = bf2f(u.x >> 16);
  f[2] = bf2f(u.y & 0xffffu); f[3] = bf2f(u.y >> 16);
  f[4] = bf2f(u.z & 0xffffu); f[5] = bf2f(u.z >> 16);
  f[6] = bf2f(u.w & 0xffffu); f[7] = bf2f(u.w >> 16);
}

struct WcvtArgs { const float* W[3]; u16* Wb[3]; };
struct PFArgs { const float* X[3]; const u16* Wb[3]; const float* bias[3]; u16* P[3]; };

// ---------------- W fp32 -> bf16 (3 weights, one launch) ----------------
__global__ __launch_bounds__(256) void wcvt(WcvtArgs a) {
  const int idx = blockIdx.x * 256 + threadIdx.x;  // < 3*16384 float4-units
  const int which = idx >> 14, off = (idx & 16383) * 4;
  float4 v = *(const float4*)&a.W[which][off];
  ushort4 o = {f2bf(v.x), f2bf(v.y), f2bf(v.z), f2bf(v.w)};
  *(ushort4*)&a.Wb[which][off] = o;
}

// ------- proj (x3, transpose fused): Pt[l][co] = sum_c X[c][l]*W[co][c] + b -------
// Block: 128 l x 256 co, k-loop BK=32. X read directly from [C][L] fp32 (512B rows),
// transposed into LDS during staging. Both co-halves per block (X read once).
__global__ __launch_bounds__(256, 2) void proj_fused(PFArgs args) {
  __shared__ __align__(16) u16 At[128 * ATP];  // [l][k] transposed X tile
  __shared__ __align__(16) u16 Bs[256 * 32];   // [co][k] W (bf16)
  const int which = blockIdx.y >> 3, n = blockIdx.y & 7;
  const int l0 = blockIdx.x * 128;
  const int t = threadIdx.x;
  const int lane = t & 63, wave = t >> 6;
  const int fr = lane & 15, q = lane >> 4;
  const int wl = (wave >> 1) * 64, wco = (wave & 1) * 128;
  const int s32 = t & 31, rcg = t >> 5;        // A staging coords
  const int srow = t >> 2, scol = (t & 3) * 8; // B staging coords
  const float* X = args.X[which] + (size_t)n * C * LL;
  const u16* Wb = args.Wb[which];
  f32x4 acc[4][8] = {};
  float4 xv[4];
#pragma unroll
  for (int j = 0; j < 4; ++j)
    xv[j] = *(const float4*)&X[(size_t)(rcg * 4 + j) * LL + l0 + s32 * 4];
  for (int k0 = 0; k0 < C; k0 += 32) {
    __syncthreads();
#pragma unroll
    for (int s = 0; s < 4; ++s)
      gload_lds16(&Wb[(size_t)(s * 64 + srow) * C + k0 + scol],
                  &Bs[s * 2048 + wave * 512]);
    const float* xf = (const float*)xv;
#pragma unroll
    for (int li = 0; li < 4; ++li) {
      const int lp = li ^ (s32 & 3);  // permuted write order for LDS bank spread
      u32 lo = (u32)f2bf(xf[0 * 4 + lp]) | ((u32)f2bf(xf[1 * 4 + lp]) << 16);
      u32 hi = (u32)f2bf(xf[2 * 4 + lp]) | ((u32)f2bf(xf[3 * 4 + lp]) << 16);
      u32* dst = (u32*)&At[(s32 * 4 + lp) * ATP + rcg * 4];
      dst[0] = lo; dst[1] = hi;
    }
    __syncthreads();
    if (k0 + 32 < C) {
#pragma unroll
      for (int j = 0; j < 4; ++j)
        xv[j] = *(const float4*)&X[(size_t)(k0 + 32 + rcg * 4 + j) * LL + l0 + s32 * 4];
    }
    bf16x8 a[4];
#pragma unroll
    for (int i = 0; i < 4; ++i)
      a[i] = *(const bf16x8*)&At[(wl + i * 16 + fr) * ATP + q * 8];
#pragma unroll
    for (int j = 0; j < 8; ++j) {
      bf16x8 b = *(const bf16x8*)&Bs[(wco + j * 16 + fr) * 32 + q * 8];
#pragma unroll
      for (int i = 0; i < 4; ++i)
        acc[i][j] = __builtin_amdgcn_mfma_f32_16x16x32_bf16(a[i], b, acc[i][j], 0, 0, 0);
    }
  }
  const float* bias = args.bias[which];
  u16* P = args.P[which] + (size_t)n * LL * C;
  float bb[8];
#pragma unroll
  for (int j = 0; j < 8; ++j) bb[j] = bias[wco + j * 16 + fr];
#pragma unroll
  for (int i = 0; i < 4; ++i)
#pragma unroll
    for (int r = 0; r < 4; ++r) {
      const int lrow = l0 + wl + i * 16 + q * 4 + r;
#pragma unroll
      for (int j = 0; j < 8; ++j)
        P[(size_t)lrow * C + wco + j * 16 + fr] = f2bf(acc[i][j][r] + bb[j]);
    }
}

// -------- ctx partials (one pass, no-max softmax): pctx += exp(K)[l,k]*V[l,v] --------
// grid (SEG, NB). Full 512B-row async staging; wave handles 2 heads.
__global__ __launch_bounds__(256) void ctx_part(const u16* __restrict__ Kt,
    const u16* __restrict__ Vt, float* __restrict__ pctx, float* __restrict__ psum) {
  __shared__ __align__(16) u16 Ks[16 * 256];
  __shared__ __align__(16) u16 Vs[16 * 256];
  const int seg = blockIdx.x, n = blockIdx.y;
  const int t = threadIdx.x, lane = t & 63, wave = t >> 6;
  const int l0 = seg * SL;
  const u16* KtN = Kt + (size_t)n * LL * C;
  const u16* VtN = Vt + (size_t)n * LL * C;
  const int k4 = (lane & 7) * 4, v8 = lane >> 3;
  float acc[2][4][4] = {};
  float ssum[2][4] = {};
  for (int ls = 0; ls < SL; ls += 16) {
    __syncthreads();
#pragma unroll
    for (int i = 0; i < 2; ++i) {
      const int r = wave * 4 + i * 2;
      gload_lds16(&KtN[(size_t)(l0 + ls + r) * C + lane * 8], &Ks[r * 256]);
      gload_lds16(&VtN[(size_t)(l0 + ls + r) * C + lane * 8], &Vs[r * 256]);
    }
    __syncthreads();
#pragma unroll
    for (int hh = 0; hh < 2; ++hh) {
      const int h = wave * 2 + hh;
#pragma unroll
      for (int l = 0; l < 16; ++l) {
        ushort4 ku = *(const ushort4*)&Ks[l * 256 + h * 32 + k4];
        ushort4 vu = *(const ushort4*)&Vs[l * 256 + h * 32 + v8 * 4];
        float ek[4] = {__expf(bf2f(ku.x)), __expf(bf2f(ku.y)),
                       __expf(bf2f(ku.z)), __expf(bf2f(ku.w))};
        float vf[4] = {bf2f(vu.x), bf2f(vu.y), bf2f(vu.z), bf2f(vu.w)};
#pragma unroll
        for (int i = 0; i < 4; ++i)
#pragma unroll
          for (int j = 0; j < 4; ++j) acc[hh][i][j] = fmaf(ek[i], vf[j], acc[hh][i][j]);
        if (v8 == 0)
#pragma unroll
          for (int i = 0; i < 4; ++i) ssum[hh][i] += ek[i];
      }
    }
  }
#pragma unroll
  for (int hh = 0; hh < 2; ++hh) {
    const int h = wave * 2 + hh;
    const size_t pb = ((size_t)seg * NH + n * 8 + h) * 1024;
#pragma unroll
    for (int i = 0; i < 4; ++i)
#pragma unroll
      for (int j = 0; j < 4; ++j)
        pctx[pb + (size_t)(k4 + i) * 32 + v8 * 4 + j] = acc[hh][i][j];
    if (v8 == 0) {
      const size_t sb = ((size_t)seg * NH + n * 8 + h) * 32;
#pragma unroll
      for (int i = 0; i < 4; ++i) psum[sb + k4 + i] = ssum[hh][i];
    }
  }
}

// ---------------- reduce partials + normalize: ctx = (sum pctx) / (sum psum) ----------------
__global__ __launch_bounds__(256) void ctx_reduce(const float* __restrict__ pctx,
    const float* __restrict__ psum, float* __restrict__ ctx) {
  const int idx = blockIdx.x * 256 + threadIdx.x;  // < NH*1024
  const int nh = idx >> 10, e = idx & 1023, k = e >> 5;
  float s = 0.f, ss = 0.f;
  for (int g = 0; g < SEG; ++g) {
    s += pctx[(size_t)(g * NH + nh) * 1024 + e];
    ss += psum[(size_t)(g * NH + nh) * 32 + k];
  }
  ctx[idx] = s / ss;
}

// ---------------- fuse: M_n[o, h*32+k] = sum_v Wr[o,h*32+v]*ctx[n,h,k,v], bf16 ----------------
__global__ __launch_bounds__(256) void mfuse(const float* __restrict__ Wr,
    const float* __restrict__ ctx, u16* __restrict__ M) {
  const int idx = blockIdx.x * 256 + threadIdx.x;  // < NB*C*C
  const int hk = idx & 255;
  const int o = (idx >> 8) & 255;
  const int n = idx >> 16;
  const int h = hk >> 5, k = hk & 31;
  const float* wr = Wr + (size_t)o * C + h * HC;
  const float* cx = ctx + ((size_t)(n * HEADS + h) * HC + k) * HC;
  float s = 0.f;
#pragma unroll
  for (int v = 0; v < HC; ++v) s = fmaf(wr[v], cx[v], s);
  M[idx] = f2bf(s);
}

// ---- out[co][l] = sum_k M[co][k]*softmaxQ[l][k] + br[co] + Xq[co][l], fp32 ----
// Block: 64 l x 256 co. Q staged+softmaxed ONCE into persistent LDS panel;
// M staged async per (coh, k-step).
__global__ __launch_bounds__(256) void out_fused(const u16* __restrict__ Qt,
    const u16* __restrict__ Mb, const float* __restrict__ br,
    const float* __restrict__ Xq, float* __restrict__ out) {
  __shared__ __align__(16) u16 Qp[64 * QPP];  // softmaxed Q, [l][k]
  __shared__ __align__(16) u16 As[128 * 32];  // M tile [co][k]
  const int n = blockIdx.y, l0 = blockIdx.x * 64;
  const int t = threadIdx.x, lane = t & 63, wave = t >> 6;
  const int fr = lane & 15, q = lane >> 4;
  const int wcoL = (wave >> 1) * 64, wl = (wave & 1) * 32;
  const u16* QtN = Qt + (size_t)n * LL * C;
#pragma unroll
  for (int p = 0; p < 2; ++p) {
    const int row = p * 32 + (t >> 3);
    const int g = t & 7;
    const uint4* src = (const uint4*)&QtN[(size_t)(l0 + row) * C + g * 32];
    uint4 u0 = src[0], u1 = src[1], u2 = src[2], u3 = src[3];
    float v[32];
    unpack8(u0, v); unpack8(u1, v + 8); unpack8(u2, v + 16); unpack8(u3, v + 24);
    float e[32], s = 0.f;
#pragma unroll
    for (int j = 0; j < 32; ++j) { e[j] = __expf(v[j]); s += e[j]; }
    const float r = 1.0f / s;
    uint4* drow = (uint4*)&Qp[row * QPP + g * 32];
#pragma unroll
    for (int b4 = 0; b4 < 4; ++b4) {
      union { uint4 u; u16 h[8]; } o;
#pragma unroll
      for (int j = 0; j < 8; ++j) o.h[j] = f2bf(e[b4 * 8 + j] * r);
      drow[b4] = o.u;
    }
  }
  f32x4 acc[2][4][2] = {};
  const u16* MbN = Mb + (size_t)n * C * C;
  const int srow = t >> 2, scol = (t & 3) * 8;
  for (int coh = 0; coh < 2; ++coh)
    for (int k0 = 0; k0 < C; k0 += 32) {
      __syncthreads();
#pragma unroll
      for (int s = 0; s < 2; ++s)
        gload_lds16(&MbN[(size_t)(coh * 128 + s * 64 + srow) * C + k0 + scol],
                    &As[s * 2048 + wave * 512]);
      __syncthreads();
      bf16x8 a[4], b[2];
#pragma unroll
      for (int i = 0; i < 4; ++i)
        a[i] = *(const bf16x8*)&As[(wcoL + i * 16 + fr) * 32 + q * 8];
#pragma unroll
      for (int j = 0; j < 2; ++j)
        b[j] = *(const bf16x8*)&Qp[(wl + j * 16 + fr) * QPP + k0 + q * 8];
#pragma unroll
      for (int i = 0; i < 4; ++i)
#pragma unroll
        for (int j = 0; j < 2; ++j)
          acc[coh][i][j] = __builtin_amdgcn_mfma_f32_16x16x32_bf16(a[i], b[j], acc[coh][i][j], 0, 0, 0);
    }
  const float* XqN = Xq + (size_t)n * C * LL;
  float* On = out + (size_t)n * C * LL;
#pragma unroll
  for (int coh = 0; coh < 2; ++coh)
#pragma unroll
    for (int i = 0; i < 4; ++i)
#pragma unroll
      for (int r = 0; r < 4; ++r) {
        const int co = coh * 128 + wcoL + i * 16 + q * 4 + r;
        const float bb = br[co];
#pragma unroll
        for (int j = 0; j < 2; ++j) {
          const int l = l0 + wl + j * 16 + fr;
          const size_t off = (size_t)co * LL + l;
          On[off] = acc[coh][i][j][r] + bb + XqN[off];
        }
      }
}

extern "C" void kernel_launch(void* const* d_in, const int* in_sizes, int n_in,
                              void* d_out, int out_size, void* d_ws, size_t ws_size,
                              hipStream_t stream) {
  const float* Xq = (const float*)d_in[0];
  const float* Xk = (const float*)d_in[1];
  const float* Xv = (const float*)d_in[2];
  const float* Wq = (const float*)d_in[3];
  const float* bq = (const float*)d_in[4];
  const float* Wk = (const float*)d_in[5];
  const float* bk = (const float*)d_in[6];
  const float* Wv = (const float*)d_in[7];
  const float* bv = (const float*)d_in[8];
  const float* Wr = (const float*)d_in[9];
  const float* br = (const float*)d_in[10];
  float* out = (float*)d_out;

  char* ws = (char*)d_ws;
  const size_t nelem = (size_t)NB * LL * C;  // per [L][C] bf16 buffer
  u16* Qt = (u16*)ws;
  u16* Kt = (u16*)(ws + nelem * 2);
  u16* Vt = (u16*)(ws + nelem * 4);
  char* p = ws + nelem * 6;
  u16* Wqb = (u16*)p; p += C * C * 2;
  u16* Wkb = (u16*)p; p += C * C * 2;
  u16* Wvb = (u16*)p; p += C * C * 2;
  float* pctx = (float*)p; p += (size_t)SEG * NH * HC * HC * 4;
  float* psum = (float*)p; p += (size_t)SEG * NH * HC * 4;
  float* ctx = (float*)p;  p += (size_t)NH * HC * HC * 4;
  u16* Mb = (u16*)p;

  WcvtArgs wa;
  wa.W[0] = Wq; wa.W[1] = Wk; wa.W[2] = Wv;
  wa.Wb[0] = Wqb; wa.Wb[1] = Wkb; wa.Wb[2] = Wvb;
  wcvt<<<192, 256, 0, stream>>>(wa);

  PFArgs pa;
  pa.X[0] = Xq; pa.X[1] = Xk; pa.X[2] = Xv;
  pa.Wb[0] = Wqb; pa.Wb[1] = Wkb; pa.Wb[2] = Wvb;
  pa.bias[0] = bq; pa.bias[1] = bk; pa.bias[2] = bv;
  pa.P[0] = Qt; pa.P[1] = Kt; pa.P[2] = Vt;
  proj_fused<<<dim3(50, 24), 256, 0, stream>>>(pa);

  ctx_part<<<dim3(SEG, NB), 256, 0, stream>>>(Kt, Vt, pctx, psum);
  ctx_reduce<<<NH * HC * HC / 256, 256, 0, stream>>>(pctx, psum, ctx);
  mfuse<<<NB * C * C / 256, 256, 0, stream>>>(Wr, ctx, Mb);
  out_fused<<<dim3(100, NB), 256, 0, stream>>>(Qt, Mb, br, Xq, out);
}